// Round 1
// baseline (635.002 us; speedup 1.0000x reference)
//
#include <hip/hip_runtime.h>

#define N_NODES 50000
#define N_EDGES 800000
#define F_IN    128
#define H_DIM   64
#define C_DIM   10

// ---------------------------------------------------------------- degree
__global__ __launch_bounds__(256) void deg_kernel(const int* __restrict__ cols,
                                                  const float* __restrict__ w,
                                                  float* __restrict__ deg) {
    int e = blockIdx.x * 256 + threadIdx.x;
    if (e < N_EDGES) atomicAdd(&deg[cols[e]], w[e]);
}

// ---------------------------------------------------------------- norm = dinv[row]*w*dinv[col]
__global__ __launch_bounds__(256) void norm_kernel(const int* __restrict__ rows,
                                                   const int* __restrict__ cols,
                                                   const float* __restrict__ w,
                                                   const float* __restrict__ deg,
                                                   float* __restrict__ norm) {
    int e = blockIdx.x * 256 + threadIdx.x;
    if (e < N_EDGES) {
        float dr = deg[rows[e]];
        float dc = deg[cols[e]];
        float ir = dr > 0.f ? rsqrtf(dr) : 0.f;
        float ic = dc > 0.f ? rsqrtf(dc) : 0.f;
        norm[e] = ir * w[e] * ic;
    }
}

// ---------------------------------------------------------------- GEMM: out[N,64] = X[N,K] @ W[64,K]^T
// block = 256 threads, handles 64 nodes (16 chunks of 4). W staged in LDS (padded
// rows, float4 reads; pad K+4 keeps rows 16B-aligned and spreads banks).
template <int K>
__global__ __launch_bounds__(256) void gemm_nk64(const float* __restrict__ X,
                                                 const float* __restrict__ W,
                                                 float* __restrict__ out) {
    constexpr int PAD = K + 4;
    __shared__ float Ws[64 * PAD];
    __shared__ float xs[4][K];

    for (int i = threadIdx.x; i < 64 * K; i += 256)
        Ws[(i / K) * PAD + (i % K)] = W[i];

    const int j  = threadIdx.x & 63;   // output feature (lane)
    const int ln = threadIdx.x >> 6;   // local node within chunk (wave id)
    const int base = blockIdx.x * 64;

    for (int chunk = 0; chunk < 16; ++chunk) {
        const int n0 = base + chunk * 4;
        __syncthreads();               // protect xs reuse (also covers Ws on chunk 0)
        for (int i = threadIdx.x; i < 4 * K; i += 256) {
            int nn = n0 + i / K;
            xs[i / K][i % K] = (nn < N_NODES) ? X[nn * K + (i % K)] : 0.f;
        }
        __syncthreads();
        const int n = n0 + ln;
        const float4* wv = reinterpret_cast<const float4*>(&Ws[j * PAD]);
        const float4* xv = reinterpret_cast<const float4*>(&xs[ln][0]);
        float acc = 0.f;
#pragma unroll
        for (int k4 = 0; k4 < K / 4; ++k4) {
            float4 a = xv[k4];
            float4 b = wv[k4];
            acc += a.x * b.x + a.y * b.y + a.z * b.z + a.w * b.w;
        }
        if (n < N_NODES) out[n * 64 + j] = acc;
    }
}

// ---------------------------------------------------------------- GEMM3: out[N,10] = X[N,64] @ W[10,64]^T
__global__ __launch_bounds__(256) void gemm3_kernel(const float* __restrict__ X,
                                                    const float* __restrict__ W,
                                                    float* __restrict__ out) {
    __shared__ float Ws[C_DIM * H_DIM];
    for (int i = threadIdx.x; i < C_DIM * H_DIM; i += 256) Ws[i] = W[i];
    __syncthreads();
    int idx = blockIdx.x * 256 + threadIdx.x;
    if (idx < N_NODES * C_DIM) {
        int n = idx / C_DIM, c = idx % C_DIM;
        const float* xr = X + n * H_DIM;
        const float* wr = Ws + c * H_DIM;
        float acc = 0.f;
#pragma unroll
        for (int k = 0; k < H_DIM; ++k) acc += xr[k] * wr[k];
        out[idx] = acc;
    }
}

// ---------------------------------------------------------------- init agg buffer with bias
__global__ __launch_bounds__(256) void init_bias64(float* __restrict__ agg,
                                                   const float* __restrict__ b) {
    int idx = blockIdx.x * 256 + threadIdx.x;
    if (idx < N_NODES * H_DIM) agg[idx] = b[idx & 63];
}

__global__ __launch_bounds__(256) void init_bias10(float* __restrict__ agg,
                                                   const float* __restrict__ b) {
    int idx = blockIdx.x * 256 + threadIdx.x;
    if (idx < N_NODES * C_DIM) agg[idx] = b[idx % C_DIM];
}

// ---------------------------------------------------------------- scatter: agg[col] += norm * h[row]  (F=64)
// One wave per edge; lane = feature. 256B coalesced load + 256B coalesced atomic.
__global__ __launch_bounds__(256) void scatter64_kernel(const int* __restrict__ rows,
                                                        const int* __restrict__ cols,
                                                        const float* __restrict__ norm,
                                                        const float* __restrict__ h,
                                                        float* __restrict__ agg) {
    const int lane   = threadIdx.x & 63;
    int wid          = (blockIdx.x * 256 + threadIdx.x) >> 6;
    const int stride = (gridDim.x * 256) >> 6;
    for (int e = wid; e < N_EDGES; e += stride) {
        int r = rows[e];
        int c = cols[e];
        float nm = norm[e];
        float v = h[r * 64 + lane] * nm;
        atomicAdd(&agg[c * 64 + lane], v);
    }
}

// ---------------------------------------------------------------- scatter F=10 (layer 3)
__global__ __launch_bounds__(256) void scatter10_kernel(const int* __restrict__ rows,
                                                        const int* __restrict__ cols,
                                                        const float* __restrict__ norm,
                                                        const float* __restrict__ h,
                                                        float* __restrict__ agg) {
    int idx = blockIdx.x * 256 + threadIdx.x;
    if (idx < N_EDGES * C_DIM) {
        int e = idx / C_DIM, c = idx % C_DIM;
        float v = h[rows[e] * C_DIM + c] * norm[e];
        atomicAdd(&agg[cols[e] * C_DIM + c], v);
    }
}

// ---------------------------------------------------------------- softmax over C=10
__global__ __launch_bounds__(256) void softmax_kernel(const float* __restrict__ logits,
                                                      float* __restrict__ soft) {
    int n = blockIdx.x * 256 + threadIdx.x;
    if (n < N_NODES) {
        float v[C_DIM];
        float m = -1e30f;
#pragma unroll
        for (int c = 0; c < C_DIM; ++c) { v[c] = logits[n * C_DIM + c]; m = fmaxf(m, v[c]); }
        float s = 0.f;
#pragma unroll
        for (int c = 0; c < C_DIM; ++c) { v[c] = __expf(v[c] - m); s += v[c]; }
        float inv = 1.f / s;
#pragma unroll
        for (int c = 0; c < C_DIM; ++c) soft[n * C_DIM + c] = v[c] * inv;
    }
}

// ================================================================ launch
extern "C" void kernel_launch(void* const* d_in, const int* in_sizes, int n_in,
                              void* d_out, int out_size, void* d_ws, size_t ws_size,
                              hipStream_t stream) {
    const float* x  = (const float*)d_in[0];
    const int*   ei = (const int*)d_in[1];
    const float* ew = (const float*)d_in[2];
    const float* W1 = (const float*)d_in[3];
    const float* b1 = (const float*)d_in[4];
    const float* W2 = (const float*)d_in[5];
    const float* b2 = (const float*)d_in[6];
    const float* W3 = (const float*)d_in[7];
    const float* b3 = (const float*)d_in[8];
    const int* rows = ei;            // edge_index[0]
    const int* cols = ei + N_EDGES;  // edge_index[1]

    float* ws   = (float*)d_ws;
    float* deg  = ws;                 // 50000 floats
    float* norm = ws + 50000;         // 800000 floats
    float* bufA = ws + 850000;        // N*64 = 3.2M floats
    float* bufB = bufA + N_NODES * H_DIM;

    float* logits = (float*)d_out;               // [N, 10]
    float* soft   = logits + N_NODES * C_DIM;    // [N, 10]
    float* h3     = soft;                        // temp: gemm3 output, consumed before softmax writes

    const int EB  = (N_EDGES + 255) / 256;               // 3125
    const int GB  = (N_NODES + 63) / 64;                 // 782
    const int IB64 = (N_NODES * H_DIM + 255) / 256;      // 12500
    const int IB10 = (N_NODES * C_DIM + 255) / 256;      // 1954
    const int SB10 = (N_EDGES * C_DIM + 255) / 256;      // 31250
    const int NB  = (N_NODES + 255) / 256;               // 196

    // deg + norm (reused by all 3 layers)
    hipMemsetAsync(deg, 0, N_NODES * sizeof(float), stream);
    deg_kernel<<<EB, 256, 0, stream>>>(cols, ew, deg);
    norm_kernel<<<EB, 256, 0, stream>>>(rows, cols, ew, deg, norm);

    // layer 1: h1 = x@W1^T -> bufA ; agg -> bufB (init with b1)
    gemm_nk64<F_IN><<<GB, 256, 0, stream>>>(x, W1, bufA);
    init_bias64<<<IB64, 256, 0, stream>>>(bufB, b1);
    scatter64_kernel<<<4096, 256, 0, stream>>>(rows, cols, norm, bufA, bufB);

    // layer 2: h2 = bufB@W2^T -> bufA ; agg -> bufB (init with b2, bufB free after gemm)
    gemm_nk64<H_DIM><<<GB, 256, 0, stream>>>(bufB, W2, bufA);
    init_bias64<<<IB64, 256, 0, stream>>>(bufB, b2);
    scatter64_kernel<<<4096, 256, 0, stream>>>(rows, cols, norm, bufA, bufB);

    // layer 3: h3 = bufB@W3^T -> h3 (staged in soft region) ; logits = scatter + b3
    gemm3_kernel<<<IB10, 256, 0, stream>>>(bufB, W3, h3);
    init_bias10<<<IB10, 256, 0, stream>>>(logits, b3);
    scatter10_kernel<<<SB10, 256, 0, stream>>>(rows, cols, norm, h3, logits);

    // softmax (reads logits, overwrites h3/soft region)
    softmax_kernel<<<NB, 256, 0, stream>>>(logits, soft);
}

// Round 2
// 361.479 us; speedup vs baseline: 1.7567x; 1.7567x over previous
//
#include <hip/hip_runtime.h>

#define N_NODES 50000
#define N_EDGES 800000
#define F_IN    128
#define H_DIM   64
#define C_DIM   10
#define CPAD    16      // padded feature stride for aggregation passes
#define SCAN_BLOCKS ((N_NODES + 255) / 256)   // 196

// ---------------------------------------------------------------- histogram: deg (weighted) + cnt (int)
__global__ __launch_bounds__(256) void hist_kernel(const int* __restrict__ cols,
                                                   const float* __restrict__ w,
                                                   float* __restrict__ deg,
                                                   int* __restrict__ cnt) {
    int e = blockIdx.x * 256 + threadIdx.x;
    if (e < N_EDGES) {
        int c = cols[e];
        atomicAdd(&deg[c], w[e]);
        atomicAdd(&cnt[c], 1);
    }
}

// ---------------------------------------------------------------- norm = dinv[row]*w*dinv[col]
__global__ __launch_bounds__(256) void norm_kernel(const int* __restrict__ rows,
                                                   const int* __restrict__ cols,
                                                   const float* __restrict__ w,
                                                   const float* __restrict__ deg,
                                                   float* __restrict__ norm) {
    int e = blockIdx.x * 256 + threadIdx.x;
    if (e < N_EDGES) {
        float dr = deg[rows[e]];
        float dc = deg[cols[e]];
        float ir = dr > 0.f ? rsqrtf(dr) : 0.f;
        float ic = dc > 0.f ? rsqrtf(dc) : 0.f;
        norm[e] = ir * w[e] * ic;
    }
}

// ---------------------------------------------------------------- exclusive scan of cnt -> rowptr (3 kernels)
__global__ __launch_bounds__(256) void scan_block_kernel(const int* __restrict__ cnt,
                                                         int* __restrict__ excl,
                                                         int* __restrict__ partials) {
    __shared__ int s[256];
    int i = blockIdx.x * 256 + threadIdx.x;
    int v = (i < N_NODES) ? cnt[i] : 0;
    s[threadIdx.x] = v;
    __syncthreads();
    for (int off = 1; off < 256; off <<= 1) {
        int t = (threadIdx.x >= off) ? s[threadIdx.x - off] : 0;
        __syncthreads();
        s[threadIdx.x] += t;
        __syncthreads();
    }
    if (i < N_NODES) excl[i] = s[threadIdx.x] - v;
    if (threadIdx.x == 255) partials[blockIdx.x] = s[255];
}

__global__ __launch_bounds__(256) void scan_partials_kernel(int* __restrict__ partials) {
    __shared__ int s[256];
    int t = threadIdx.x;
    int v = (t < SCAN_BLOCKS) ? partials[t] : 0;
    s[t] = v;
    __syncthreads();
    for (int off = 1; off < 256; off <<= 1) {
        int x = (t >= off) ? s[t - off] : 0;
        __syncthreads();
        s[t] += x;
        __syncthreads();
    }
    if (t < SCAN_BLOCKS) partials[t] = s[t] - v;   // exclusive
}

__global__ __launch_bounds__(256) void scan_add_kernel(const int* __restrict__ excl,
                                                       const int* __restrict__ partials,
                                                       int* __restrict__ rowptr) {
    int i = blockIdx.x * 256 + threadIdx.x;
    if (i < N_NODES) rowptr[i] = excl[i] + partials[i >> 8];
    if (i == 0) rowptr[N_NODES] = N_EDGES;
}

// ---------------------------------------------------------------- CSR fill (by col)
__global__ __launch_bounds__(256) void fill_kernel(const int* __restrict__ rows,
                                                   const int* __restrict__ cols,
                                                   const float* __restrict__ norm,
                                                   const int* __restrict__ rowptr,
                                                   int* __restrict__ cursor,
                                                   int* __restrict__ rowp,
                                                   float* __restrict__ normp) {
    int e = blockIdx.x * 256 + threadIdx.x;
    if (e < N_EDGES) {
        int c = cols[e];
        int pos = rowptr[c] + atomicAdd(&cursor[c], 1);
        rowp[pos]  = rows[e];
        normp[pos] = norm[e];
    }
}

// ---------------------------------------------------------------- weight composition
// T1 = W2 @ W1  [64,128]
__global__ __launch_bounds__(256) void prep_T1(const float* __restrict__ W2,
                                               const float* __restrict__ W1,
                                               float* __restrict__ T1) {
    int idx = blockIdx.x * 256 + threadIdx.x;
    if (idx < H_DIM * F_IN) {
        int i = idx >> 7, f = idx & 127;
        float a = 0.f;
#pragma unroll
        for (int k = 0; k < H_DIM; ++k) a += W2[i * H_DIM + k] * W1[k * F_IN + f];
        T1[idx] = a;
    }
}

// T2 = W3 @ T1  [10,128]
__global__ __launch_bounds__(256) void prep_T2(const float* __restrict__ W3,
                                               const float* __restrict__ T1,
                                               float* __restrict__ T2) {
    int idx = blockIdx.x * 256 + threadIdx.x;
    if (idx < C_DIM * F_IN) {
        int c = idx >> 7, f = idx & 127;
        float a = 0.f;
#pragma unroll
        for (int k = 0; k < H_DIM; ++k) a += W3[c * H_DIM + k] * T1[k * F_IN + f];
        T2[idx] = a;
    }
}

// v1 = W3 @ (W2 @ b1), v2 = W3 @ b2   (both [10])
__global__ __launch_bounds__(64) void prep_bias(const float* __restrict__ W2,
                                                const float* __restrict__ W3,
                                                const float* __restrict__ b1,
                                                const float* __restrict__ b2,
                                                float* __restrict__ v1,
                                                float* __restrict__ v2) {
    __shared__ float u[H_DIM];
    int t = threadIdx.x;
    float a = 0.f;
#pragma unroll
    for (int k = 0; k < H_DIM; ++k) a += W2[t * H_DIM + k] * b1[k];
    u[t] = a;
    __syncthreads();
    if (t < C_DIM) {
        float x = 0.f, y = 0.f;
#pragma unroll
        for (int k = 0; k < H_DIM; ++k) {
            float w = W3[t * H_DIM + k];
            x += w * u[k];
            y += w * b2[k];
        }
        v1[t] = x;
        v2[t] = y;
    }
}

// ---------------------------------------------------------------- z[N,16pad] = x @ T2^T  (cols 10..15 zero)
__global__ __launch_bounds__(256) void gemm_z(const float* __restrict__ X,
                                              const float* __restrict__ T2,
                                              float* __restrict__ z) {
    __shared__ float xs[64][132];   // 64 nodes x 128 (+4 pad)
    __shared__ float ts[16][132];   // 16 out-features x 128 (+4 pad), rows 10..15 = 0

    for (int i = threadIdx.x; i < 16 * F_IN; i += 256) {
        int c = i >> 7, f = i & 127;
        ts[c][f] = (c < C_DIM) ? T2[c * F_IN + f] : 0.f;
    }
    const int base = blockIdx.x * 64;
    for (int i = threadIdx.x; i < 64 * 32; i += 256) {     // float4 granules
        int ln = i >> 5, f4 = i & 31;
        int n = base + ln;
        float4 v = (n < N_NODES) ? reinterpret_cast<const float4*>(X)[n * 32 + f4]
                                 : make_float4(0.f, 0.f, 0.f, 0.f);
        *reinterpret_cast<float4*>(&xs[ln][f4 * 4]) = v;
    }
    __syncthreads();

    const int c = threadIdx.x & 15;
    const int g = threadIdx.x >> 4;                         // 0..15
    const float4* tr = reinterpret_cast<const float4*>(&ts[c][0]);
    const float4* x0 = reinterpret_cast<const float4*>(&xs[g][0]);
    const float4* x1 = reinterpret_cast<const float4*>(&xs[g + 16][0]);
    const float4* x2 = reinterpret_cast<const float4*>(&xs[g + 32][0]);
    const float4* x3 = reinterpret_cast<const float4*>(&xs[g + 48][0]);
    float a0 = 0.f, a1 = 0.f, a2 = 0.f, a3 = 0.f;
#pragma unroll
    for (int f4 = 0; f4 < 32; ++f4) {
        float4 b = tr[f4];
        float4 p;
        p = x0[f4]; a0 += p.x * b.x + p.y * b.y + p.z * b.z + p.w * b.w;
        p = x1[f4]; a1 += p.x * b.x + p.y * b.y + p.z * b.z + p.w * b.w;
        p = x2[f4]; a2 += p.x * b.x + p.y * b.y + p.z * b.z + p.w * b.w;
        p = x3[f4]; a3 += p.x * b.x + p.y * b.y + p.z * b.z + p.w * b.w;
    }
    int n0 = base + g;
    if (n0      < N_NODES) z[(n0     ) * CPAD + c] = a0;
    if (n0 + 16 < N_NODES) z[(n0 + 16) * CPAD + c] = a1;
    if (n0 + 32 < N_NODES) z[(n0 + 32) * CPAD + c] = a2;
    if (n0 + 48 < N_NODES) z[(n0 + 48) * CPAD + c] = a3;
}

// ---------------------------------------------------------------- aggregation: out[n,:] = sum_e norm_e * in[row_e,:]
// 16 threads per node (lane = padded feature). in/out stride CPAD=16.
__global__ __launch_bounds__(256) void gather16_kernel(const int* __restrict__ rowptr,
                                                       const int* __restrict__ rowp,
                                                       const float* __restrict__ normp,
                                                       const float* __restrict__ zin,
                                                       float* __restrict__ zout) {
    int t = blockIdx.x * 256 + threadIdx.x;
    int n = t >> 4;
    int c = t & 15;
    if (n >= N_NODES) return;
    int beg = rowptr[n], end = rowptr[n + 1];
    float acc = 0.f;
    for (int k = beg; k < end; ++k) {
        int r    = rowp[k];         // uniform within the 16-lane group -> broadcast
        float nm = normp[k];
        acc += nm * zin[r * CPAD + c];
    }
    zout[n * CPAD + c] = acc;
}

// ---------------------------------------------------------------- s1[n] = sum norm over in-edges
__global__ __launch_bounds__(256) void s1_kernel(const int* __restrict__ rowptr,
                                                 const float* __restrict__ normp,
                                                 float* __restrict__ s1) {
    int n = blockIdx.x * 256 + threadIdx.x;
    if (n >= N_NODES) return;
    int beg = rowptr[n], end = rowptr[n + 1];
    float a = 0.f;
    for (int k = beg; k < end; ++k) a += normp[k];
    s1[n] = a;
}

// ---------------------------------------------------------------- s2 = A s1
__global__ __launch_bounds__(256) void s2_kernel(const int* __restrict__ rowptr,
                                                 const int* __restrict__ rowp,
                                                 const float* __restrict__ normp,
                                                 const float* __restrict__ s1,
                                                 float* __restrict__ s2) {
    int n = blockIdx.x * 256 + threadIdx.x;
    if (n >= N_NODES) return;
    int beg = rowptr[n], end = rowptr[n + 1];
    float a = 0.f;
    for (int k = beg; k < end; ++k) a += normp[k] * s1[rowp[k]];
    s2[n] = a;
}

// ---------------------------------------------------------------- logits + softmax
__global__ __launch_bounds__(256) void final_kernel(const float* __restrict__ g3,
                                                    const float* __restrict__ s1,
                                                    const float* __restrict__ s2,
                                                    const float* __restrict__ v1,
                                                    const float* __restrict__ v2,
                                                    const float* __restrict__ b3,
                                                    float* __restrict__ logits,
                                                    float* __restrict__ soft) {
    __shared__ float sv1[C_DIM], sv2[C_DIM], sb3[C_DIM];
    if (threadIdx.x < C_DIM) {
        sv1[threadIdx.x] = v1[threadIdx.x];
        sv2[threadIdx.x] = v2[threadIdx.x];
        sb3[threadIdx.x] = b3[threadIdx.x];
    }
    __syncthreads();
    int n = blockIdx.x * 256 + threadIdx.x;
    if (n >= N_NODES) return;
    float a = s2[n], b = s1[n];
    float l[C_DIM];
    float m = -1e30f;
#pragma unroll
    for (int c = 0; c < C_DIM; ++c) {
        l[c] = g3[n * CPAD + c] + a * sv1[c] + b * sv2[c] + sb3[c];
        m = fmaxf(m, l[c]);
    }
    float s = 0.f;
#pragma unroll
    for (int c = 0; c < C_DIM; ++c) { l[c] = __expf(l[c] - m); s += l[c]; }
    float inv = 1.f / s;
#pragma unroll
    for (int c = 0; c < C_DIM; ++c) {
        float e = l[c];
        logits[n * C_DIM + c] = logf(e) + m + logf(s) - logf(s); // placeholder avoided below
        soft[n * C_DIM + c]   = e * inv;
    }
}

// NOTE: final_kernel above must write the true logits; rewritten cleanly here:
__global__ __launch_bounds__(256) void final_kernel2(const float* __restrict__ g3,
                                                     const float* __restrict__ s1,
                                                     const float* __restrict__ s2,
                                                     const float* __restrict__ v1,
                                                     const float* __restrict__ v2,
                                                     const float* __restrict__ b3,
                                                     float* __restrict__ logits,
                                                     float* __restrict__ soft) {
    __shared__ float sv1[C_DIM], sv2[C_DIM], sb3[C_DIM];
    if (threadIdx.x < C_DIM) {
        sv1[threadIdx.x] = v1[threadIdx.x];
        sv2[threadIdx.x] = v2[threadIdx.x];
        sb3[threadIdx.x] = b3[threadIdx.x];
    }
    __syncthreads();
    int n = blockIdx.x * 256 + threadIdx.x;
    if (n >= N_NODES) return;
    float a = s2[n], b = s1[n];
    float l[C_DIM], e[C_DIM];
    float m = -1e30f;
#pragma unroll
    for (int c = 0; c < C_DIM; ++c) {
        l[c] = g3[n * CPAD + c] + a * sv1[c] + b * sv2[c] + sb3[c];
        m = fmaxf(m, l[c]);
    }
    float s = 0.f;
#pragma unroll
    for (int c = 0; c < C_DIM; ++c) { e[c] = __expf(l[c] - m); s += e[c]; }
    float inv = 1.f / s;
#pragma unroll
    for (int c = 0; c < C_DIM; ++c) {
        logits[n * C_DIM + c] = l[c];
        soft[n * C_DIM + c]   = e[c] * inv;
    }
}

// ================================================================ launch
extern "C" void kernel_launch(void* const* d_in, const int* in_sizes, int n_in,
                              void* d_out, int out_size, void* d_ws, size_t ws_size,
                              hipStream_t stream) {
    const float* x  = (const float*)d_in[0];
    const int*   ei = (const int*)d_in[1];
    const float* ew = (const float*)d_in[2];
    const float* W1 = (const float*)d_in[3];
    const float* b1 = (const float*)d_in[4];
    const float* W2 = (const float*)d_in[5];
    const float* b2 = (const float*)d_in[6];
    const float* W3 = (const float*)d_in[7];
    const float* b3 = (const float*)d_in[8];
    const int* rows = ei;            // edge_index[0]
    const int* cols = ei + N_EDGES;  // edge_index[1]

    char* ws = (char*)d_ws;
    size_t off = 0;
    auto alloc = [&](size_t elems) { void* p = ws + off; off += elems * 4; return p; };

    float* deg      = (float*)alloc(N_NODES);
    float* norm     = (float*)alloc(N_EDGES);
    int*   cnt      = (int*)  alloc(N_NODES);
    int*   cursor   = (int*)  alloc(N_NODES);
    int*   excl     = (int*)  alloc(N_NODES);
    int*   partials = (int*)  alloc(256);
    int*   rowptr   = (int*)  alloc(N_NODES + 4);
    int*   rowp     = (int*)  alloc(N_EDGES);
    float* normp    = (float*)alloc(N_EDGES);
    float* bufA     = (float*)alloc(N_NODES * CPAD);
    float* bufB     = (float*)alloc(N_NODES * CPAD);
    float* s1       = (float*)alloc(N_NODES);
    float* s2       = (float*)alloc(N_NODES);
    float* T1       = (float*)alloc(H_DIM * F_IN);
    float* T2       = (float*)alloc(C_DIM * F_IN);
    float* v1       = (float*)alloc(16);
    float* v2       = (float*)alloc(16);

    float* logits = (float*)d_out;
    float* soft   = logits + N_NODES * C_DIM;

    const int EB = (N_EDGES + 255) / 256;                 // 3125
    const int NB = (N_NODES + 255) / 256;                 // 196
    const int GZ = (N_NODES + 63) / 64;                   // 782
    const int GA = (N_NODES * CPAD + 255) / 256;          // 3125

    hipMemsetAsync(deg,    0, N_NODES * sizeof(float), stream);
    hipMemsetAsync(cnt,    0, N_NODES * sizeof(int),   stream);
    hipMemsetAsync(cursor, 0, N_NODES * sizeof(int),   stream);

    // normalization + CSR build
    hist_kernel<<<EB, 256, 0, stream>>>(cols, ew, deg, cnt);
    norm_kernel<<<EB, 256, 0, stream>>>(rows, cols, ew, deg, norm);
    scan_block_kernel<<<SCAN_BLOCKS, 256, 0, stream>>>(cnt, excl, partials);
    scan_partials_kernel<<<1, 256, 0, stream>>>(partials);
    scan_add_kernel<<<SCAN_BLOCKS, 256, 0, stream>>>(excl, partials, rowptr);
    fill_kernel<<<EB, 256, 0, stream>>>(rows, cols, norm, rowptr, cursor, rowp, normp);

    // weight composition + z = x @ T2^T
    prep_T1<<<(H_DIM * F_IN + 255) / 256, 256, 0, stream>>>(W2, W1, T1);
    prep_T2<<<(C_DIM * F_IN + 255) / 256, 256, 0, stream>>>(W3, T1, T2);
    prep_bias<<<1, 64, 0, stream>>>(W2, W3, b1, b2, v1, v2);
    gemm_z<<<GZ, 256, 0, stream>>>(x, T2, bufA);

    // three aggregation passes: bufA -> bufB -> bufA -> bufB
    gather16_kernel<<<GA, 256, 0, stream>>>(rowptr, rowp, normp, bufA, bufB);
    gather16_kernel<<<GA, 256, 0, stream>>>(rowptr, rowp, normp, bufB, bufA);
    gather16_kernel<<<GA, 256, 0, stream>>>(rowptr, rowp, normp, bufA, bufB);

    // bias propagation vectors
    s1_kernel<<<NB, 256, 0, stream>>>(rowptr, normp, s1);
    s2_kernel<<<NB, 256, 0, stream>>>(rowptr, rowp, normp, s1, s2);

    // logits + softmax
    final_kernel2<<<NB, 256, 0, stream>>>(bufB, s1, s2, v1, v2, b3, logits, soft);
}

// Round 3
// 327.064 us; speedup vs baseline: 1.9415x; 1.1052x over previous
//
#include <hip/hip_runtime.h>

#define N_NODES 50000
#define N_EDGES 800000
#define F_IN    128
#define H_DIM   64
#define C_DIM   10
#define CPAD    16
#define SCAN_BLOCKS ((N_NODES + 255) / 256)   // 196

// ---------------------------------------------------------------- cnt histogram (1 atomic/edge)
__global__ __launch_bounds__(256) void hist_kernel(const int* __restrict__ cols,
                                                   int* __restrict__ cnt) {
    int e = blockIdx.x * 256 + threadIdx.x;
    if (e < N_EDGES) atomicAdd(&cnt[cols[e]], 1);
}

// ---------------------------------------------------------------- exclusive scan of cnt -> rowptr, cursor
__global__ __launch_bounds__(256) void scan_block_kernel(const int* __restrict__ cnt,
                                                         int* __restrict__ excl,
                                                         int* __restrict__ partials) {
    __shared__ int s[256];
    int i = blockIdx.x * 256 + threadIdx.x;
    int v = (i < N_NODES) ? cnt[i] : 0;
    s[threadIdx.x] = v;
    __syncthreads();
    for (int off = 1; off < 256; off <<= 1) {
        int t = (threadIdx.x >= off) ? s[threadIdx.x - off] : 0;
        __syncthreads();
        s[threadIdx.x] += t;
        __syncthreads();
    }
    if (i < N_NODES) excl[i] = s[threadIdx.x] - v;
    if (threadIdx.x == 255) partials[blockIdx.x] = s[255];
}

__global__ __launch_bounds__(256) void scan_partials_kernel(int* __restrict__ partials) {
    __shared__ int s[256];
    int t = threadIdx.x;
    int v = (t < SCAN_BLOCKS) ? partials[t] : 0;
    s[t] = v;
    __syncthreads();
    for (int off = 1; off < 256; off <<= 1) {
        int x = (t >= off) ? s[t - off] : 0;
        __syncthreads();
        s[t] += x;
        __syncthreads();
    }
    if (t < SCAN_BLOCKS) partials[t] = s[t] - v;   // exclusive
}

__global__ __launch_bounds__(256) void scan_add_kernel(const int* __restrict__ excl,
                                                       const int* __restrict__ partials,
                                                       int* __restrict__ rowptr,
                                                       int* __restrict__ cursor) {
    int i = blockIdx.x * 256 + threadIdx.x;
    if (i < N_NODES) {
        int v = excl[i] + partials[i >> 8];
        rowptr[i] = v;
        cursor[i] = v;
    }
    if (i == 0) rowptr[N_NODES] = N_EDGES;
}

// ---------------------------------------------------------------- CSR fill: edata[pos] = {row, w_bits}
__global__ __launch_bounds__(256) void fill_kernel(const int* __restrict__ rows,
                                                   const int* __restrict__ cols,
                                                   const float* __restrict__ ew,
                                                   int* __restrict__ cursor,
                                                   int2* __restrict__ edata) {
    int e = blockIdx.x * 256 + threadIdx.x;
    if (e < N_EDGES) {
        int c = cols[e];
        int pos = atomicAdd(&cursor[c], 1);
        edata[pos] = make_int2(rows[e], __float_as_int(ew[e]));
    }
}

// ---------------------------------------------------------------- dinv[n] = rsqrt(sum_seg w)
__global__ __launch_bounds__(256) void dinv_kernel(const int* __restrict__ rowptr,
                                                   const int2* __restrict__ edata,
                                                   float* __restrict__ dinv) {
    int n = blockIdx.x * 256 + threadIdx.x;
    if (n >= N_NODES) return;
    int beg = rowptr[n], end = rowptr[n + 1];
    float d = 0.f;
    for (int k = beg; k < end; ++k) d += __int_as_float(edata[k].y);
    dinv[n] = d > 0.f ? rsqrtf(d) : 0.f;
}

// ---------------------------------------------------------------- normp (in-place into edata.y) + s1
__global__ __launch_bounds__(256) void normp_s1_kernel(const int* __restrict__ rowptr,
                                                       const float* __restrict__ dinv,
                                                       int2* __restrict__ edata,
                                                       float* __restrict__ s1) {
    int n = blockIdx.x * 256 + threadIdx.x;
    if (n >= N_NODES) return;
    int beg = rowptr[n], end = rowptr[n + 1];
    float di = dinv[n];
    float a = 0.f;
    for (int k = beg; k < end; ++k) {
        int2 ed = edata[k];
        float nm = di * __int_as_float(ed.y) * dinv[ed.x];
        edata[k] = make_int2(ed.x, __float_as_int(nm));
        a += nm;
    }
    s1[n] = a;
}

// ---------------------------------------------------------------- s2 = A s1
__global__ __launch_bounds__(256) void s2_kernel(const int* __restrict__ rowptr,
                                                 const int2* __restrict__ edata,
                                                 const float* __restrict__ s1,
                                                 float* __restrict__ s2) {
    int n = blockIdx.x * 256 + threadIdx.x;
    if (n >= N_NODES) return;
    int beg = rowptr[n], end = rowptr[n + 1];
    float a = 0.f;
    for (int k = beg; k < end; ++k) {
        int2 ed = edata[k];
        a += __int_as_float(ed.y) * s1[ed.x];
    }
    s2[n] = a;
}

// ---------------------------------------------------------------- weight composition
__global__ __launch_bounds__(256) void prep_T1(const float* __restrict__ W2,
                                               const float* __restrict__ W1,
                                               float* __restrict__ T1) {
    int idx = blockIdx.x * 256 + threadIdx.x;
    if (idx < H_DIM * F_IN) {
        int i = idx >> 7, f = idx & 127;
        float a = 0.f;
#pragma unroll
        for (int k = 0; k < H_DIM; ++k) a += W2[i * H_DIM + k] * W1[k * F_IN + f];
        T1[idx] = a;
    }
}

__global__ __launch_bounds__(256) void prep_T2(const float* __restrict__ W3,
                                               const float* __restrict__ T1,
                                               float* __restrict__ T2) {
    int idx = blockIdx.x * 256 + threadIdx.x;
    if (idx < C_DIM * F_IN) {
        int c = idx >> 7, f = idx & 127;
        float a = 0.f;
#pragma unroll
        for (int k = 0; k < H_DIM; ++k) a += W3[c * H_DIM + k] * T1[k * F_IN + f];
        T2[idx] = a;
    }
}

__global__ __launch_bounds__(64) void prep_bias(const float* __restrict__ W2,
                                                const float* __restrict__ W3,
                                                const float* __restrict__ b1,
                                                const float* __restrict__ b2,
                                                float* __restrict__ v1,
                                                float* __restrict__ v2) {
    __shared__ float u[H_DIM];
    int t = threadIdx.x;
    float a = 0.f;
#pragma unroll
    for (int k = 0; k < H_DIM; ++k) a += W2[t * H_DIM + k] * b1[k];
    u[t] = a;
    __syncthreads();
    if (t < C_DIM) {
        float x = 0.f, y = 0.f;
#pragma unroll
        for (int k = 0; k < H_DIM; ++k) {
            float w = W3[t * H_DIM + k];
            x += w * u[k];
            y += w * b2[k];
        }
        v1[t] = x;
        v2[t] = y;
    }
}

// ---------------------------------------------------------------- z[N,16pad] = x @ T2^T (cols 10..15 zero)
__global__ __launch_bounds__(256) void gemm_z(const float* __restrict__ X,
                                              const float* __restrict__ T2,
                                              float* __restrict__ z) {
    __shared__ float xs[64][132];
    __shared__ float ts[16][132];

    for (int i = threadIdx.x; i < 16 * F_IN; i += 256) {
        int c = i >> 7, f = i & 127;
        ts[c][f] = (c < C_DIM) ? T2[c * F_IN + f] : 0.f;
    }
    const int base = blockIdx.x * 64;
    for (int i = threadIdx.x; i < 64 * 32; i += 256) {
        int ln = i >> 5, f4 = i & 31;
        int n = base + ln;
        float4 v = (n < N_NODES) ? reinterpret_cast<const float4*>(X)[n * 32 + f4]
                                 : make_float4(0.f, 0.f, 0.f, 0.f);
        *reinterpret_cast<float4*>(&xs[ln][f4 * 4]) = v;
    }
    __syncthreads();

    const int c = threadIdx.x & 15;
    const int g = threadIdx.x >> 4;
    const float4* tr = reinterpret_cast<const float4*>(&ts[c][0]);
    const float4* x0 = reinterpret_cast<const float4*>(&xs[g][0]);
    const float4* x1 = reinterpret_cast<const float4*>(&xs[g + 16][0]);
    const float4* x2 = reinterpret_cast<const float4*>(&xs[g + 32][0]);
    const float4* x3 = reinterpret_cast<const float4*>(&xs[g + 48][0]);
    float a0 = 0.f, a1 = 0.f, a2 = 0.f, a3 = 0.f;
#pragma unroll
    for (int f4 = 0; f4 < 32; ++f4) {
        float4 b = tr[f4];
        float4 p;
        p = x0[f4]; a0 += p.x * b.x + p.y * b.y + p.z * b.z + p.w * b.w;
        p = x1[f4]; a1 += p.x * b.x + p.y * b.y + p.z * b.z + p.w * b.w;
        p = x2[f4]; a2 += p.x * b.x + p.y * b.y + p.z * b.z + p.w * b.w;
        p = x3[f4]; a3 += p.x * b.x + p.y * b.y + p.z * b.z + p.w * b.w;
    }
    int n0 = base + g;
    if (n0      < N_NODES) z[(n0     ) * CPAD + c] = a0;
    if (n0 + 16 < N_NODES) z[(n0 + 16) * CPAD + c] = a1;
    if (n0 + 32 < N_NODES) z[(n0 + 32) * CPAD + c] = a2;
    if (n0 + 48 < N_NODES) z[(n0 + 48) * CPAD + c] = a3;
}

// ---------------------------------------------------------------- wave-per-node gather: 4 edges in flight
// lane = sub*16 + c; sub in [0,4) walks edges, c = padded feature.
__global__ __launch_bounds__(256) void gatherW_kernel(const int* __restrict__ rowptr,
                                                      const int2* __restrict__ edata,
                                                      const float* __restrict__ zin,
                                                      float* __restrict__ zout) {
    int n = (blockIdx.x * 256 + threadIdx.x) >> 6;
    if (n >= N_NODES) return;
    int lane = threadIdx.x & 63;
    int sub = lane >> 4, c = lane & 15;
    int beg = rowptr[n], end = rowptr[n + 1];
    float acc = 0.f;
    for (int k = beg + sub; k < end; k += 4) {
        int2 ed = edata[k];
        acc += __int_as_float(ed.y) * zin[ed.x * CPAD + c];
    }
    acc += __shfl_xor(acc, 32);
    acc += __shfl_xor(acc, 16);
    if (lane < 16) zout[n * CPAD + lane] = acc;
}

// ---------------------------------------------------------------- final gather + bias + softmax (fused)
__global__ __launch_bounds__(256) void gather_final_kernel(const int* __restrict__ rowptr,
                                                           const int2* __restrict__ edata,
                                                           const float* __restrict__ zin,
                                                           const float* __restrict__ s1,
                                                           const float* __restrict__ s2,
                                                           const float* __restrict__ v1,
                                                           const float* __restrict__ v2,
                                                           const float* __restrict__ b3,
                                                           float* __restrict__ logits,
                                                           float* __restrict__ soft) {
    int n = (blockIdx.x * 256 + threadIdx.x) >> 6;
    if (n >= N_NODES) return;
    int lane = threadIdx.x & 63;
    int sub = lane >> 4, c = lane & 15;
    int beg = rowptr[n], end = rowptr[n + 1];
    float acc = 0.f;
    for (int k = beg + sub; k < end; k += 4) {
        int2 ed = edata[k];
        acc += __int_as_float(ed.y) * zin[ed.x * CPAD + c];
    }
    acc += __shfl_xor(acc, 32);
    acc += __shfl_xor(acc, 16);       // every lane now holds full sum for its c

    float a1 = s1[n], a2 = s2[n];
    float l = (c < C_DIM) ? acc + a2 * v1[c] + a1 * v2[c] + b3[c] : -1e30f;
    float m = l;
#pragma unroll
    for (int d = 8; d >= 1; d >>= 1) m = fmaxf(m, __shfl_xor(m, d));
    float e = (c < C_DIM) ? __expf(l - m) : 0.f;
    float s = e;
#pragma unroll
    for (int d = 8; d >= 1; d >>= 1) s += __shfl_xor(s, d);
    if (lane < C_DIM) {
        logits[n * C_DIM + lane] = l;
        soft[n * C_DIM + lane]   = e / s;
    }
}

// ================================================================ launch
extern "C" void kernel_launch(void* const* d_in, const int* in_sizes, int n_in,
                              void* d_out, int out_size, void* d_ws, size_t ws_size,
                              hipStream_t stream) {
    const float* x  = (const float*)d_in[0];
    const int*   ei = (const int*)d_in[1];
    const float* ew = (const float*)d_in[2];
    const float* W1 = (const float*)d_in[3];
    const float* b1 = (const float*)d_in[4];
    const float* W2 = (const float*)d_in[5];
    const float* b2 = (const float*)d_in[6];
    const float* W3 = (const float*)d_in[7];
    const float* b3 = (const float*)d_in[8];
    const int* rows = ei;
    const int* cols = ei + N_EDGES;

    char* ws = (char*)d_ws;
    size_t off = 0;
    auto alloc = [&](size_t elems) { void* p = ws + off; off += ((elems + 3) & ~size_t(3)) * 4; return p; };

    int*   cnt      = (int*)  alloc(N_NODES);
    int*   excl     = (int*)  alloc(N_NODES);
    int*   partials = (int*)  alloc(256);
    int*   rowptr   = (int*)  alloc(N_NODES + 4);
    int*   cursor   = (int*)  alloc(N_NODES);
    float* dinv     = (float*)alloc(N_NODES);
    float* s1       = (float*)alloc(N_NODES);
    float* s2       = (float*)alloc(N_NODES);
    int2*  edata    = (int2*) alloc(N_EDGES * 2);
    float* bufA     = (float*)alloc(N_NODES * CPAD);
    float* bufB     = (float*)alloc(N_NODES * CPAD);
    float* T1       = (float*)alloc(H_DIM * F_IN);
    float* T2       = (float*)alloc(C_DIM * F_IN);
    float* v1       = (float*)alloc(16);
    float* v2       = (float*)alloc(16);

    float* logits = (float*)d_out;
    float* soft   = logits + N_NODES * C_DIM;

    const int EB = (N_EDGES + 255) / 256;          // 3125
    const int NB = (N_NODES + 255) / 256;          // 196
    const int GZ = (N_NODES + 63) / 64;            // 782
    const int WB = (N_NODES * 64) / 256;           // 12500 (wave-per-node)

    hipMemsetAsync(cnt, 0, N_NODES * sizeof(int), stream);

    // CSR build
    hist_kernel<<<EB, 256, 0, stream>>>(cols, cnt);
    scan_block_kernel<<<SCAN_BLOCKS, 256, 0, stream>>>(cnt, excl, partials);
    scan_partials_kernel<<<1, 256, 0, stream>>>(partials);
    scan_add_kernel<<<SCAN_BLOCKS, 256, 0, stream>>>(excl, partials, rowptr, cursor);
    fill_kernel<<<EB, 256, 0, stream>>>(rows, cols, ew, cursor, edata);

    // normalization from CSR (no atomics)
    dinv_kernel<<<NB, 256, 0, stream>>>(rowptr, edata, dinv);
    normp_s1_kernel<<<NB, 256, 0, stream>>>(rowptr, dinv, edata, s1);
    s2_kernel<<<NB, 256, 0, stream>>>(rowptr, edata, s1, s2);

    // weight composition + z = x @ T2^T
    prep_T1<<<(H_DIM * F_IN + 255) / 256, 256, 0, stream>>>(W2, W1, T1);
    prep_T2<<<(C_DIM * F_IN + 255) / 256, 256, 0, stream>>>(W3, T1, T2);
    prep_bias<<<1, 64, 0, stream>>>(W2, W3, b1, b2, v1, v2);
    gemm_z<<<GZ, 256, 0, stream>>>(x, T2, bufA);

    // A^3 z: two plain gathers + fused final
    gatherW_kernel<<<WB, 256, 0, stream>>>(rowptr, edata, bufA, bufB);
    gatherW_kernel<<<WB, 256, 0, stream>>>(rowptr, edata, bufB, bufA);
    gather_final_kernel<<<WB, 256, 0, stream>>>(rowptr, edata, bufA, s1, s2, v1, v2, b3,
                                                logits, soft);
}

// Round 4
// 287.986 us; speedup vs baseline: 2.2050x; 1.1357x over previous
//
#include <hip/hip_runtime.h>

#define N_NODES 50000
#define N_EDGES 800000
#define F_IN    128
#define H_DIM   64
#define C_DIM   10
#define CPAD    16
#define SCAN_BLOCKS ((N_NODES + 255) / 256)   // 196

// ---------------------------------------------------------------- hist + rank (1 atomic/edge, rank saved)
__global__ __launch_bounds__(256) void hist_rank_kernel(const int* __restrict__ cols,
                                                        int* __restrict__ cnt,
                                                        int* __restrict__ rank) {
    int e = blockIdx.x * 256 + threadIdx.x;
    if (e < N_EDGES) rank[e] = atomicAdd(&cnt[cols[e]], 1);
}

// ---------------------------------------------------------------- exclusive scan of cnt -> rowptr
__global__ __launch_bounds__(256) void scan_block_kernel(const int* __restrict__ cnt,
                                                         int* __restrict__ excl,
                                                         int* __restrict__ partials) {
    __shared__ int s[256];
    int i = blockIdx.x * 256 + threadIdx.x;
    int v = (i < N_NODES) ? cnt[i] : 0;
    s[threadIdx.x] = v;
    __syncthreads();
    for (int off = 1; off < 256; off <<= 1) {
        int t = (threadIdx.x >= off) ? s[threadIdx.x - off] : 0;
        __syncthreads();
        s[threadIdx.x] += t;
        __syncthreads();
    }
    if (i < N_NODES) excl[i] = s[threadIdx.x] - v;
    if (threadIdx.x == 255) partials[blockIdx.x] = s[255];
}

__global__ __launch_bounds__(256) void scan_partials_kernel(int* __restrict__ partials) {
    __shared__ int s[256];
    int t = threadIdx.x;
    int v = (t < SCAN_BLOCKS) ? partials[t] : 0;
    s[t] = v;
    __syncthreads();
    for (int off = 1; off < 256; off <<= 1) {
        int x = (t >= off) ? s[t - off] : 0;
        __syncthreads();
        s[t] += x;
        __syncthreads();
    }
    if (t < SCAN_BLOCKS) partials[t] = s[t] - v;   // exclusive
}

__global__ __launch_bounds__(256) void scan_add_kernel(const int* __restrict__ excl,
                                                       const int* __restrict__ partials,
                                                       int* __restrict__ rowptr) {
    int i = blockIdx.x * 256 + threadIdx.x;
    if (i < N_NODES) rowptr[i] = excl[i] + partials[i >> 8];
    if (i == 0) rowptr[N_NODES] = N_EDGES;
}

// ---------------------------------------------------------------- CSR fill: NO atomics (pos = rowptr + rank)
__global__ __launch_bounds__(256) void fill_kernel(const int* __restrict__ rows,
                                                   const int* __restrict__ cols,
                                                   const float* __restrict__ ew,
                                                   const int* __restrict__ rowptr,
                                                   const int* __restrict__ rank,
                                                   int2* __restrict__ edata) {
    int e = blockIdx.x * 256 + threadIdx.x;
    if (e < N_EDGES) {
        int pos = rowptr[cols[e]] + rank[e];
        edata[pos] = make_int2(rows[e], __float_as_int(ew[e]));
    }
}

// ---------------------------------------------------------------- dinv[n] = rsqrt(sum_seg w)
__global__ __launch_bounds__(256) void dinv_kernel(const int* __restrict__ rowptr,
                                                   const int2* __restrict__ edata,
                                                   float* __restrict__ dinv) {
    int n = blockIdx.x * 256 + threadIdx.x;
    if (n >= N_NODES) return;
    int beg = rowptr[n], end = rowptr[n + 1];
    float d = 0.f;
    for (int k = beg; k < end; ++k) d += __int_as_float(edata[k].y);
    dinv[n] = d > 0.f ? rsqrtf(d) : 0.f;
}

// ---------------------------------------------------------------- normp (in-place) + s1 (also into bufA col 10)
__global__ __launch_bounds__(256) void normp_s1_kernel(const int* __restrict__ rowptr,
                                                       const float* __restrict__ dinv,
                                                       int2* __restrict__ edata,
                                                       float* __restrict__ s1,
                                                       float* __restrict__ bufA) {
    int n = blockIdx.x * 256 + threadIdx.x;
    if (n >= N_NODES) return;
    int beg = rowptr[n], end = rowptr[n + 1];
    float di = dinv[n];
    float a = 0.f;
    for (int k = beg; k < end; ++k) {
        int2 ed = edata[k];
        float nm = di * __int_as_float(ed.y) * dinv[ed.x];
        edata[k] = make_int2(ed.x, __float_as_int(nm));
        a += nm;
    }
    s1[n] = a;
    bufA[n * CPAD + 10] = a;   // s1 rides as feature 10 -> pass1 yields s2 in bufB col 10
}

// ---------------------------------------------------------------- fused weight composition (1 block)
__global__ __launch_bounds__(256) void prep_all(const float* __restrict__ W1,
                                                const float* __restrict__ W2,
                                                const float* __restrict__ W3,
                                                const float* __restrict__ b1,
                                                const float* __restrict__ b2,
                                                float* __restrict__ T2g,
                                                float* __restrict__ v1,
                                                float* __restrict__ v2) {
    __shared__ float T1s[H_DIM * F_IN];   // 32 KB
    __shared__ float u[H_DIM];
    int t = threadIdx.x;
    for (int idx = t; idx < H_DIM * F_IN; idx += 256) {
        int i = idx >> 7, f = idx & 127;
        float a = 0.f;
#pragma unroll
        for (int k = 0; k < H_DIM; ++k) a += W2[i * H_DIM + k] * W1[k * F_IN + f];
        T1s[idx] = a;
    }
    if (t < H_DIM) {
        float a = 0.f;
#pragma unroll
        for (int k = 0; k < H_DIM; ++k) a += W2[t * H_DIM + k] * b1[k];
        u[t] = a;
    }
    __syncthreads();
    for (int idx = t; idx < C_DIM * F_IN; idx += 256) {
        int c = idx >> 7, f = idx & 127;
        float a = 0.f;
#pragma unroll
        for (int k = 0; k < H_DIM; ++k) a += W3[c * H_DIM + k] * T1s[k * F_IN + f];
        T2g[idx] = a;
    }
    if (t < C_DIM) {
        float xx = 0.f, yy = 0.f;
#pragma unroll
        for (int k = 0; k < H_DIM; ++k) {
            float w = W3[t * H_DIM + k];
            xx += w * u[k];
            yy += w * b2[k];
        }
        v1[t] = xx;
        v2[t] = yy;
    }
}

// ---------------------------------------------------------------- z[N,16pad] = x @ T2^T (32 nodes/block)
__global__ __launch_bounds__(256) void gemm_z(const float* __restrict__ X,
                                              const float* __restrict__ T2,
                                              float* __restrict__ z) {
    __shared__ float xs[32][132];   // 16.9 KB
    __shared__ float ts[16][132];   // 8.4 KB

    for (int i = threadIdx.x; i < 16 * F_IN; i += 256) {
        int c = i >> 7;
        ts[c][i & 127] = (c < C_DIM) ? T2[i] : 0.f;
    }
    const int base = blockIdx.x * 32;
    for (int i = threadIdx.x; i < 32 * 32; i += 256) {
        int ln = i >> 5, f4 = i & 31;
        int n = base + ln;
        float4 v = (n < N_NODES) ? reinterpret_cast<const float4*>(X)[n * 32 + f4]
                                 : make_float4(0.f, 0.f, 0.f, 0.f);
        *reinterpret_cast<float4*>(&xs[ln][f4 * 4]) = v;
    }
    __syncthreads();

    const int c = threadIdx.x & 15;
    const int g = threadIdx.x >> 4;                 // 0..15
    const float4* tr = reinterpret_cast<const float4*>(&ts[c][0]);
    const float4* x0 = reinterpret_cast<const float4*>(&xs[g][0]);
    const float4* x1 = reinterpret_cast<const float4*>(&xs[g + 16][0]);
    float a0 = 0.f, a1 = 0.f;
#pragma unroll
    for (int f4 = 0; f4 < 32; ++f4) {
        float4 b = tr[f4];
        float4 p = x0[f4];
        a0 += p.x * b.x + p.y * b.y + p.z * b.z + p.w * b.w;
        float4 q = x1[f4];
        a1 += q.x * b.x + q.y * b.y + q.z * b.z + q.w * b.w;
    }
    int n0 = base + g;
    if (n0      < N_NODES) z[(n0     ) * CPAD + c] = a0;
    if (n0 + 16 < N_NODES) z[(n0 + 16) * CPAD + c] = a1;
}

// ---------------------------------------------------------------- wave-per-node gather (4 edges in flight)
__global__ __launch_bounds__(256) void gatherW_kernel(const int* __restrict__ rowptr,
                                                      const int2* __restrict__ edata,
                                                      const float* __restrict__ zin,
                                                      float* __restrict__ zout) {
    int n = (blockIdx.x * 256 + threadIdx.x) >> 6;
    if (n >= N_NODES) return;
    int lane = threadIdx.x & 63;
    int sub = lane >> 4, c = lane & 15;
    int beg = rowptr[n], end = rowptr[n + 1];
    float acc = 0.f;
    for (int k = beg + sub; k < end; k += 4) {
        int2 ed = edata[k];
        acc += __int_as_float(ed.y) * zin[ed.x * CPAD + c];
    }
    acc += __shfl_xor(acc, 32);
    acc += __shfl_xor(acc, 16);
    if (lane < 16) zout[n * CPAD + lane] = acc;
}

// ---------------------------------------------------------------- final gather + bias + softmax (fused)
__global__ __launch_bounds__(256) void gather_final_kernel(const int* __restrict__ rowptr,
                                                           const int2* __restrict__ edata,
                                                           const float* __restrict__ zin,
                                                           const float* __restrict__ s1,
                                                           const float* __restrict__ s2buf,  // bufB: col 10 = s2
                                                           const float* __restrict__ v1,
                                                           const float* __restrict__ v2,
                                                           const float* __restrict__ b3,
                                                           float* __restrict__ logits,
                                                           float* __restrict__ soft) {
    int n = (blockIdx.x * 256 + threadIdx.x) >> 6;
    if (n >= N_NODES) return;
    int lane = threadIdx.x & 63;
    int sub = lane >> 4, c = lane & 15;
    int beg = rowptr[n], end = rowptr[n + 1];
    float acc = 0.f;
    for (int k = beg + sub; k < end; k += 4) {
        int2 ed = edata[k];
        acc += __int_as_float(ed.y) * zin[ed.x * CPAD + c];
    }
    acc += __shfl_xor(acc, 32);
    acc += __shfl_xor(acc, 16);       // full sum for feature c in every lane

    float a1 = s1[n];
    float a2 = s2buf[n * CPAD + 10];  // s2 = (A s1)[n]
    float l = (c < C_DIM) ? acc + a2 * v1[c] + a1 * v2[c] + b3[c] : -1e30f;
    float m = l;
#pragma unroll
    for (int d = 8; d >= 1; d >>= 1) m = fmaxf(m, __shfl_xor(m, d));
    float e = (c < C_DIM) ? __expf(l - m) : 0.f;
    float s = e;
#pragma unroll
    for (int d = 8; d >= 1; d >>= 1) s += __shfl_xor(s, d);
    if (lane < C_DIM) {
        logits[n * C_DIM + lane] = l;
        soft[n * C_DIM + lane]   = e / s;
    }
}

// ================================================================ launch
extern "C" void kernel_launch(void* const* d_in, const int* in_sizes, int n_in,
                              void* d_out, int out_size, void* d_ws, size_t ws_size,
                              hipStream_t stream) {
    const float* x  = (const float*)d_in[0];
    const int*   ei = (const int*)d_in[1];
    const float* ew = (const float*)d_in[2];
    const float* W1 = (const float*)d_in[3];
    const float* b1 = (const float*)d_in[4];
    const float* W2 = (const float*)d_in[5];
    const float* b2 = (const float*)d_in[6];
    const float* W3 = (const float*)d_in[7];
    const float* b3 = (const float*)d_in[8];
    const int* rows = ei;
    const int* cols = ei + N_EDGES;

    char* ws = (char*)d_ws;
    size_t off = 0;
    auto alloc = [&](size_t elems) { void* p = ws + off; off += ((elems + 3) & ~size_t(3)) * 4; return p; };

    int*   cnt      = (int*)  alloc(N_NODES);
    int*   rank     = (int*)  alloc(N_EDGES);
    int*   excl     = (int*)  alloc(N_NODES);
    int*   partials = (int*)  alloc(256);
    int*   rowptr   = (int*)  alloc(N_NODES + 4);
    float* dinv     = (float*)alloc(N_NODES);
    float* s1       = (float*)alloc(N_NODES);
    int2*  edata    = (int2*) alloc(N_EDGES * 2);
    float* bufA     = (float*)alloc(N_NODES * CPAD);
    float* bufB     = (float*)alloc(N_NODES * CPAD);
    float* T2       = (float*)alloc(C_DIM * F_IN);
    float* v1       = (float*)alloc(16);
    float* v2       = (float*)alloc(16);

    float* logits = (float*)d_out;
    float* soft   = logits + N_NODES * C_DIM;

    const int EB = (N_EDGES + 255) / 256;          // 3125
    const int NB = (N_NODES + 255) / 256;          // 196
    const int GZ = (N_NODES + 31) / 32;            // 1563
    const int WB = (N_NODES * 64) / 256;           // 12500

    hipMemsetAsync(cnt, 0, N_NODES * sizeof(int), stream);

    // CSR build (single atomic pass; fill is atomic-free via rank)
    hist_rank_kernel<<<EB, 256, 0, stream>>>(cols, cnt, rank);
    scan_block_kernel<<<SCAN_BLOCKS, 256, 0, stream>>>(cnt, excl, partials);
    scan_partials_kernel<<<1, 256, 0, stream>>>(partials);
    scan_add_kernel<<<SCAN_BLOCKS, 256, 0, stream>>>(excl, partials, rowptr);
    fill_kernel<<<EB, 256, 0, stream>>>(rows, cols, ew, rowptr, rank, edata);

    // normalization from CSR
    dinv_kernel<<<NB, 256, 0, stream>>>(rowptr, edata, dinv);

    // weights + z = x @ T2^T (writes cols 0..9, zeros 10..15)
    prep_all<<<1, 256, 0, stream>>>(W1, W2, W3, b1, b2, T2, v1, v2);
    gemm_z<<<GZ, 256, 0, stream>>>(x, T2, bufA);

    // norm in-place + s1 (also planted into bufA col 10)
    normp_s1_kernel<<<NB, 256, 0, stream>>>(rowptr, dinv, edata, s1, bufA);

    // A^3 z: pass1 -> bufB (col10 = s2), pass2 -> bufA, fused final
    gatherW_kernel<<<WB, 256, 0, stream>>>(rowptr, edata, bufA, bufB);
    gatherW_kernel<<<WB, 256, 0, stream>>>(rowptr, edata, bufB, bufA);
    gather_final_kernel<<<WB, 256, 0, stream>>>(rowptr, edata, bufA, s1, bufB, v1, v2, b3,
                                                logits, soft);
}